// Round 11
// baseline (7865.727 us; speedup 1.0000x reference)
//
#include <hip/hip_runtime.h>
#include <stdint.h>

#define B_   256
#define T_   160
#define DIN_ 40
#define H_   768
#define NG_  3072   // 4*H
#define KP0_ 1024   // 48 x-pad | 768 h | pad to 1024
#define KP12_ 1536  // 768 hin | 768 hown
#define XC_  48     // padded x columns
#define RS_  16     // h ring slots (per-XCD L2-resident recurrence window)
#define FR_  64     // barrier fast-flag rotation
#define ZP_  3200   // 32*100 floats per zred partial (stride 100: 2-way banks = free)
#define BH_  ((size_t)B_ * H_)

// LDS flag indices (values are the monotone global step counter `iter`)
#define FGO 0    // poll done (wave 4 -> stagers)
#define FST 1    // ..FST+7: stage done per wave
#define FGD 9    // ..FGD+5: gates done per gate-wave
#define FMD 15   // ..FMD+3: hin-MFMA reads done (waves 0-3)
#define FPF 19   // ..FPF+1: hin prefetch drained (waves 6,7)

typedef _Float16 f16;
typedef _Float16 half8 __attribute__((ext_vector_type(8)));
typedef float f32x4 __attribute__((ext_vector_type(4)));

#define AS1C(p) ((const __attribute__((address_space(1))) uint32_t*)(p))
#define AS3(p)  ((__attribute__((address_space(3))) uint32_t*)(p))

struct Params {
  const f16* wt0; const f16* wt1; const f16* wt2;
  const float* bq; const f16* x16;
  f16* hs0; f16* hs1;            // time-indexed inter-layer hin arrays
  f16* ring;                     // [3][RS_][B][H] intra-layer recurrence rings
  const f16* zpad; unsigned* cnt; unsigned* flgW; unsigned* claim; float* out;
};

__device__ __forceinline__ float sigmoid_f(float x) { return 1.f / (1.f + __expf(-x)); }
__device__ __forceinline__ float tanh_f(float x) {
  x = fminf(15.f, fmaxf(-15.f, x));
  float e = __expf(2.f * x);
  return (e - 1.f) / (e + 1.f);
}

__device__ __forceinline__ void spinN(volatile unsigned* s, int i0, int n, unsigned tgt) {
  for (int i = 0; i < n; ++i) { while (s[i0 + i] < tgt) {} }
  __builtin_amdgcn_sched_barrier(0);
  asm volatile("" ::: "memory");
}

// Weights -> fp16, transposed [n'][k], gate-interleaved cols n' = 4*j + g.
__global__ void conv_w(const float* __restrict__ Wi, const float* __restrict__ Wh,
                       int in_dim, int hoff, int Kp, f16* __restrict__ dst) {
  __shared__ f16 tile[64][66];
  const int k0 = blockIdx.x * 64;
  const int by = blockIdx.y;            // 0..47
  const int g = by / 12, j0 = (by % 12) * 64;
  const int tid = threadIdx.x;
  #pragma unroll
  for (int it = 0; it < 16; ++it) {
    int idx = it * 256 + tid;
    int jj = idx & 63;
    int kk = idx >> 6;
    int k = k0 + kk;
    int oc = g * H_ + j0 + jj;
    float v = 0.f;
    if (k < in_dim) v = Wi[(size_t)k * NG_ + oc];
    else if (k >= hoff && k < hoff + H_) v = Wh[(size_t)(k - hoff) * NG_ + oc];
    tile[kk][jj] = (f16)v;
  }
  __syncthreads();
  #pragma unroll
  for (int it = 0; it < 16; ++it) {
    int idx = it * 256 + tid;
    int kk = idx & 63;
    int jj = idx >> 6;
    int np = 4 * (j0 + jj) + g;
    dst[(size_t)np * Kp + k0 + kk] = tile[kk][jj];
  }
}

__global__ void conv_b(const float* __restrict__ b0, const float* __restrict__ b1,
                       const float* __restrict__ b2, float* __restrict__ bq) {
  int id = blockIdx.x * 256 + threadIdx.x;
  if (id < 3 * NG_) {
    int l = id / NG_, np = id % NG_;
    int j = np >> 2, g = np & 3;
    const float* s = (l == 0) ? b0 : (l == 1 ? b1 : b2);
    bq[id] = s[g * H_ + j];
  }
}

// x [B,T,40] fp32 -> x16 [T,B,48] fp16 (cols 40..47 zero)
__global__ void conv_x(const float* __restrict__ x, f16* __restrict__ x16) {
  int id = blockIdx.x * 256 + threadIdx.x;
  if (id >= T_ * B_ * XC_) return;
  int k = id % XC_;
  int b = (id / XC_) % B_;
  int t = id / (XC_ * B_);
  float v = (k < DIN_) ? x[(size_t)b * (T_ * DIN_) + t * DIN_ + k] : 0.f;
  x16[id] = (f16)v;
}

template<int L>
__device__ __forceinline__ void run_layer(
    const f16* __restrict__ WT, const f16* __restrict__ hin, f16* __restrict__ hs_out,
    f16* __restrict__ ring,
    const float* __restrict__ bql, const f16* __restrict__ zpad, float* __restrict__ out,
    unsigned* flg, unsigned* flgW, unsigned& iter, f16* Abuf, float* zred, float* bqs,
    volatile unsigned* sflg,
    int tid, int lane, int w, int kw, int cw, int btile, int ntile, int n0) {
  constexpr int KP  = (L == 0) ? KP0_ : KP12_;
  constexpr int KQ  = KP / 4;
  constexpr int NKT = KQ / 32;                // L0: 8, L12: 12
  constexpr int CH  = (L == 0) ? 128 : 96;    // 16B chunks per A row in addressed block

  if (tid < 96) bqs[tid] = bql[tid];

  // ---- persistent B fragments (r10-proven mapping)
  half8 breg[3 * NKT];
  #pragma unroll
  for (int ct = 0; ct < 3; ++ct) {
    #pragma unroll
    for (int kt = 0; kt < NKT; ++kt) {
      int col = n0 + cw * 48 + ct * 16 + (lane & 15);
      int k = kw * KQ + kt * 32 + (lane >> 4) * 8;
      breg[ct * NKT + kt] = *(const half8*)(WT + (size_t)col * KP + k);
    }
  }

  auto stage_hin = [&](int slot) {   // waves 6,7: hin slot -> Abuf[0..48KB)
    #pragma unroll
    for (int i = 0; i < 24; ++i) {
      int cb = (w - 6) * 1536 + i * 64;
      int idx = cb + lane;
      int row = idx / 96;
      int c = idx - row * 96;
      int cg = c ^ (row & 7);
      const f16* src = hin + ((size_t)slot * B_ + btile * 32 + row) * H_ + cg * 8;
      __builtin_amdgcn_global_load_lds(AS1C(src), AS3(Abuf + (size_t)cb * 8), 16, 0, 0);
    }
  };
  auto stage_hown = [&](int t) {     // waves 4-7: ring slot t&15 -> Abuf[48KB..96KB)
    const f16* rbase = ring + ((size_t)(t & (RS_ - 1)) * B_) * H_;
    #pragma unroll
    for (int i = 0; i < 12; ++i) {
      int cb = (w - 4) * 768 + i * 64;
      int idx = cb + lane;
      int row = idx / 96;
      int c = idx - row * 96;
      int cg = c ^ (row & 7);
      const f16* src = rbase + (size_t)(btile * 32 + row) * H_ + cg * 8;
      __builtin_amdgcn_global_load_lds(AS1C(src), AS3(Abuf + (size_t)(32 * 768 + cb * 8)), 16, 0, 0);
    }
  };
  auto stage_l0 = [&](int t) {       // all 8 waves: x16(t) + ring slot t&15
    const f16* rbase = ring + ((size_t)(t & (RS_ - 1)) * B_) * H_;
    #pragma unroll
    for (int i = 0; i < 8; ++i) {
      int cb = w * 512 + i * 64;
      int idx = cb + lane;
      int row = idx >> 7;
      int c = idx & 127;
      int cg = c ^ (row & 7);
      int b = btile * 32 + row;
      const f16* src;
      if (cg < 6)        src = hin + ((size_t)t * B_ + b) * XC_ + cg * 8;
      else if (cg < 102) src = rbase + (size_t)b * H_ + (cg - 6) * 8;
      else               src = zpad;
      __builtin_amdgcn_global_load_lds(AS1C(src), AS3(Abuf + (size_t)cb * 8), 16, 0, 0);
    }
  };
  auto do_mfma = [&](const char* Ab, int cbase, f32x4 (&acc)[2][3]) {
    #pragma unroll
    for (int kt = 0; kt < NKT; ++kt) {
      int c = cbase + kt * 4 + (lane >> 4);
      int row0 = (lane & 15);
      half8 a0 = *(const half8*)(Ab + (size_t)row0 * (CH * 16) + (size_t)(c ^ (row0 & 7)) * 16);
      int row1 = 16 + (lane & 15);
      half8 a1 = *(const half8*)(Ab + (size_t)row1 * (CH * 16) + (size_t)(c ^ (row1 & 7)) * 16);
      #pragma unroll
      for (int ct = 0; ct < 3; ++ct) {
        acc[0][ct] = __builtin_amdgcn_mfma_f32_16x16x32_f16(a0, breg[ct * NKT + kt], acc[0][ct], 0, 0, 0);
        acc[1][ct] = __builtin_amdgcn_mfma_f32_16x16x32_f16(a1, breg[ct * NKT + kt], acc[1][ct], 0, 0, 0);
      }
    }
  };
  auto zwrite = [&](int kwp, f32x4 (&acc)[2][3]) {
    float* zr = zred + (size_t)kwp * ZP_;
    #pragma unroll
    for (int rt = 0; rt < 2; ++rt)
      #pragma unroll
      for (int ct = 0; ct < 3; ++ct)
        #pragma unroll
        for (int r4 = 0; r4 < 4; ++r4)
          zr[(size_t)(rt * 16 + (lane >> 4) * 4 + r4) * 100 + cw * 48 + ct * 16 + (lane & 15)]
            = acc[rt][ct][r4];
  };

  // gate item (tid<384): row*12+jp; 8 gate cols = 2 h cols
  const int grow = tid / 12, gjp = tid - grow * 12;
  const int gb = btile * 32 + grow;
  const int ghc0 = ntile * 24 + 2 * gjp;
  float c0 = 0.f, c1 = 0.f, oa0 = 0.f, oa1 = 0.f;

  // ---- layer-entry priming: issue hin(slot 1); drained at step 0 by waves 6,7
  if (L > 0 && w >= 6) stage_hin(1);

  for (int t = 0; t <= T_; ++t) {
    ++iter;
    const unsigned it = iter;
    const bool doG = (t > 0);     // gates(t-1) -> h(t)
    const bool doM = (t < T_);    // MFMA(t)

    // ---- waves 6,7: drain prefetch (or priming), publish pf
    if (L > 0 && w >= 6 && doM) {
      asm volatile("s_waitcnt vmcnt(0)" ::: "memory");
      if (lane == 0) sflg[FPF + (w - 6)] = it;
    }

    // ---- gates(t-1): waves 0-5
    if (doG && tid < 384) {
      const float* z = zred + (size_t)grow * 100 + gjp * 8;
      f32x4 za = *(const f32x4*)(z)            + *(const f32x4*)(z + ZP_)
               + *(const f32x4*)(z + 2 * ZP_)  + *(const f32x4*)(z + 3 * ZP_);
      f32x4 zb = *(const f32x4*)(z + 4)           + *(const f32x4*)(z + 4 + ZP_)
               + *(const f32x4*)(z + 4 + 2 * ZP_) + *(const f32x4*)(z + 4 + 3 * ZP_);
      za += *(const f32x4*)(bqs + gjp * 8);
      zb += *(const f32x4*)(bqs + gjp * 8 + 4);
      float i0 = sigmoid_f(za[0]), f0 = sigmoid_f(za[1]), g0 = tanh_f(za[2]), o0 = sigmoid_f(za[3]);
      float i1 = sigmoid_f(zb[0]), f1 = sigmoid_f(zb[1]), g1 = tanh_f(zb[2]), o1 = sigmoid_f(zb[3]);
      float cn0 = f0 * c0 + i0 * g0;
      float cn1 = f1 * c1 + i1 * g1;
      c0 = cn0; c1 = cn1;
      float h0 = o0 * tanh_f(cn0);
      float h1 = o1 * tanh_f(cn1);
      f16 hh0 = (f16)h0, hh1 = (f16)h1;
      unsigned u = ((unsigned)__builtin_bit_cast(uint16_t, hh1) << 16)
                 |  (unsigned)__builtin_bit_cast(uint16_t, hh0);
      // h(t): ring (local-L2 recurrence) + time-indexed hs (next layer's hin)
      unsigned* rp = (unsigned*)(ring + ((size_t)(t & (RS_ - 1)) * B_ + gb) * H_ + ghc0);
      __hip_atomic_store(rp, u, __ATOMIC_RELAXED, __HIP_MEMORY_SCOPE_WORKGROUP);
      if (L < 2) {
        unsigned* hp = (unsigned*)(hs_out + (size_t)t * BH_ + (size_t)gb * H_ + ghc0);
        __hip_atomic_store(hp, u, __ATOMIC_RELAXED, __HIP_MEMORY_SCOPE_WORKGROUP);
      } else {
        oa0 += h0; oa1 += h1;
        if (t == T_) {
          out[(size_t)gb * H_ + ghc0]     = oa0 * (1.f / T_);
          out[(size_t)gb * H_ + ghc0 + 1] = oa1 * (1.f / T_);
        }
      }
      asm volatile("s_waitcnt vmcnt(0)" ::: "memory");
      if (lane == 0) sflg[FGD + w] = it;
    }

    // ---- wave 4: sync master (flags + poll + GO)
    if (w == 4) {
      if (doG) {
        spinN(sflg, FGD, 6, it);
        if (lane == 0) {
          __hip_atomic_store(flgW + ((size_t)(it & (FR_ - 1)) * 32 + ntile) * 32, it,
                             __ATOMIC_RELAXED, __HIP_MEMORY_SCOPE_WORKGROUP);
          __hip_atomic_store(flg + (size_t)ntile * 32, it,
                             __ATOMIC_RELAXED, __HIP_MEMORY_SCOPE_AGENT);
        }
        if (doM) {
          volatile const unsigned* fw =
              (volatile const unsigned*)(flgW + ((size_t)(it & (FR_ - 1)) * 32 + (lane & 31)) * 32);
          unsigned v = *fw;
          if (__ballot(v >= it) != ~0ull) {
            unsigned* fp = flg + (size_t)(lane & 31) * 32;
            for (;;) {
              v = __hip_atomic_load(fp, __ATOMIC_RELAXED, __HIP_MEMORY_SCOPE_AGENT);
              if (__ballot(v >= it) == ~0ull) break;
              __builtin_amdgcn_s_sleep(1);
            }
          }
        }
      }
      if (doM && lane == 0) sflg[FGO] = it;
    }

    if (doM) {
      if (L > 0) {
        if (w < 4) {
          // ---- hin path: barrier-independent MFMA
          spinN(sflg, FPF, 2, it);
          f32x4 acc[2][3] = {};
          do_mfma((const char*)Abuf, (kw & 1) * 48, acc);
          asm volatile("s_waitcnt lgkmcnt(0)" ::: "memory");
          if (lane == 0) sflg[FMD + w] = it;
          if (doG) spinN(sflg, FGD, 6, it);   // zred(t-1) readers done
          zwrite(kw, acc);
        } else {
          // ---- hown path: gated on poll
          spinN(sflg, FGO, 1, it);
          stage_hown(t);
          asm volatile("s_waitcnt vmcnt(0)" ::: "memory");
          if (lane == 0) sflg[FST + (w - 4)] = it;
          spinN(sflg, FST, 4, it);
          f32x4 acc[2][3] = {};
          do_mfma((const char*)(Abuf + 32 * 768), (kw & 1) * 48, acc);
          zwrite(kw, acc);
          if (w >= 6 && t <= T_ - 2) {
            spinN(sflg, FMD, 4, it);          // hin(t) readers done -> region free
            stage_hin(t + 2);                 // issue only; stays in flight across barrier
          }
        }
      } else {
        // ---- L0: everything post-GO
        spinN(sflg, FGO, 1, it);
        stage_l0(t);
        asm volatile("s_waitcnt vmcnt(0)" ::: "memory");
        if (lane == 0) sflg[FST + w] = it;
        spinN(sflg, FST, 8, it);
        f32x4 acc[2][3] = {};
        do_mfma((const char*)Abuf, kw * 32, acc);
        zwrite(kw, acc);
      }
    }

    asm volatile("s_waitcnt lgkmcnt(0)" ::: "memory");
    __builtin_amdgcn_s_barrier();   // raw: no vmcnt drain (prefetch stays in flight)
  }
}

__global__ __launch_bounds__(512, 2) void lstm_main(Params p) {
  __shared__ __align__(16) f16 Abuf[2 * 32 * 768];        // 96 KB
  __shared__ __align__(16) float zred[4 * ZP_];           // 51.2 KB (stride-100 partials)
  __shared__ __align__(16) float bqs[96];
  __shared__ unsigned claim_s[2];
  __shared__ unsigned sflg_s[32];

  const int tid = threadIdx.x;
  const int lane = tid & 63;
  const int w = tid >> 6;
  const int kw = w >> 1, cw = w & 1;

  if (tid < 32) sflg_s[tid] = 0;
  // dynamic XCD-local grouping (r8-r10 proven)
  if (tid == 0) {
    unsigned xcc;
    asm volatile("s_getreg_b32 %0, hwreg(HW_REG_XCC_ID)" : "=s"(xcc));
    xcc &= 7u;
    unsigned slot = __hip_atomic_fetch_add(p.claim + xcc, 1u,
                                           __ATOMIC_RELAXED, __HIP_MEMORY_SCOPE_AGENT);
    claim_s[0] = xcc;
    claim_s[1] = slot & 31u;
  }
  __syncthreads();
  const int btile = (int)claim_s[0];
  const int ntile = (int)claim_s[1];
  unsigned* flg  = p.cnt  + (size_t)btile * 1024;
  unsigned* flgW = p.flgW + (size_t)btile * (FR_ * 32 * 32);
  const int n0 = ntile * 96;
  unsigned iter = 0;
  volatile unsigned* sflg = (volatile unsigned*)sflg_s;

  f16* ring0 = p.ring;
  f16* ring1 = p.ring + (size_t)RS_ * BH_;
  f16* ring2 = p.ring + (size_t)2 * RS_ * BH_;

  run_layer<0>(p.wt0, p.x16, p.hs0, ring0, p.bq + 0 * NG_ + n0, p.zpad, p.out, flg, flgW, iter,
               Abuf, zred, bqs, sflg, tid, lane, w, kw, cw, btile, ntile, n0);
  run_layer<1>(p.wt1, p.hs0, p.hs1, ring1, p.bq + 1 * NG_ + n0, p.zpad, p.out, flg, flgW, iter,
               Abuf, zred, bqs, sflg, tid, lane, w, kw, cw, btile, ntile, n0);
  run_layer<2>(p.wt2, p.hs1, (f16*)nullptr, ring2, p.bq + 2 * NG_ + n0, p.zpad, p.out, flg, flgW, iter,
               Abuf, zred, bqs, sflg, tid, lane, w, kw, cw, btile, ntile, n0);
}

extern "C" void kernel_launch(void* const* d_in, const int* in_sizes, int n_in,
                              void* d_out, int out_size, void* d_ws, size_t ws_size,
                              hipStream_t stream) {
  const float* x   = (const float*)d_in[0];
  const float* Wi0 = (const float*)d_in[1];
  const float* Wh0 = (const float*)d_in[2];
  const float* b0  = (const float*)d_in[3];
  const float* Wi1 = (const float*)d_in[4];
  const float* Wh1 = (const float*)d_in[5];
  const float* b1  = (const float*)d_in[6];
  const float* Wi2 = (const float*)d_in[7];
  const float* Wh2 = (const float*)d_in[8];
  const float* b2  = (const float*)d_in[9];

  char* wsb = (char*)d_ws;
  size_t off = 0;
  auto nxt = [&](size_t sz) { char* p = wsb + off; off += (sz + 255) & ~(size_t)255; return p; };
  f16*      wt0  = (f16*)nxt((size_t)NG_ * KP0_ * 2);
  f16*      wt1  = (f16*)nxt((size_t)NG_ * KP12_ * 2);
  f16*      wt2  = (f16*)nxt((size_t)NG_ * KP12_ * 2);
  float*    bq   = (float*)nxt((size_t)3 * NG_ * 4);
  f16*      x16  = (f16*)nxt((size_t)T_ * B_ * XC_ * 2);
  f16*      hs0  = (f16*)nxt((size_t)(T_ + 1) * BH_ * 2);
  f16*      hs1  = (f16*)nxt((size_t)(T_ + 1) * BH_ * 2);
  f16*      ring = (f16*)nxt((size_t)3 * RS_ * BH_ * 2);
  f16*      zpad = (f16*)nxt(256);
  unsigned* cnt  = (unsigned*)nxt(8 * 1024 * 4);
  unsigned* flgW = (unsigned*)nxt((size_t)8 * FR_ * 32 * 128);
  unsigned* claim= (unsigned*)nxt(256);
  if (off > ws_size) return;

  hipMemsetAsync(ring, 0, BH_ * 2, stream);                          // h0(0)=0
  hipMemsetAsync(ring + (size_t)RS_ * BH_, 0, BH_ * 2, stream);      // h1(0)=0
  hipMemsetAsync(ring + (size_t)2 * RS_ * BH_, 0, BH_ * 2, stream);  // h2(0)=0
  hipMemsetAsync(hs0, 0, BH_ * 2, stream);
  hipMemsetAsync(hs1, 0, BH_ * 2, stream);
  hipMemsetAsync((void*)zpad, 0, 256, stream);
  hipMemsetAsync(cnt, 0, 8 * 1024 * 4, stream);
  hipMemsetAsync(flgW, 0, (size_t)8 * FR_ * 32 * 128, stream);
  hipMemsetAsync(claim, 0, 256, stream);

  hipLaunchKernelGGL(conv_w, dim3(KP0_ / 64, 48), dim3(256), 0, stream, Wi0, Wh0, DIN_, XC_, KP0_, wt0);
  hipLaunchKernelGGL(conv_w, dim3(KP12_ / 64, 48), dim3(256), 0, stream, Wi1, Wh1, H_, H_, KP12_, wt1);
  hipLaunchKernelGGL(conv_w, dim3(KP12_ / 64, 48), dim3(256), 0, stream, Wi2, Wh2, H_, H_, KP12_, wt2);
  hipLaunchKernelGGL(conv_b, dim3((3 * NG_ + 255) / 256), dim3(256), 0, stream, b0, b1, b2, bq);
  hipLaunchKernelGGL(conv_x, dim3((T_ * B_ * XC_ + 255) / 256), dim3(256), 0, stream, x, x16);

  Params prm{wt0, wt1, wt2, bq, x16, hs0, hs1, ring, zpad, cnt, flgW, claim, (float*)d_out};
  hipLaunchKernelGGL(lstm_main, dim3(256), dim3(512), 0, stream, prm);
}

// Round 12
// 5722.045 us; speedup vs baseline: 1.3746x; 1.3746x over previous
//
#include <hip/hip_runtime.h>
#include <stdint.h>

#define B_   256
#define T_   160
#define DIN_ 40
#define H_   768
#define NG_  3072   // 4*H
#define KP0_ 1024   // 48 x-pad | 768 h | pad to 1024
#define KP12_ 1536  // 768 hin | 768 hown
#define XC_  48     // padded x columns
#define RS_  16     // h ring slots (per-XCD L2-resident recurrence window)
#define FR_  64     // barrier flag rotation (iters)
#define REP_ 8      // fast-flag replicas (one per poll retry)
#define ZP_  3200   // 32*100 floats per zred partial (stride 100: conflict-light)
#define BH_  ((size_t)B_ * H_)

typedef _Float16 f16;
typedef _Float16 half8 __attribute__((ext_vector_type(8)));
typedef float f32x4 __attribute__((ext_vector_type(4)));

#define AS1C(p) ((const __attribute__((address_space(1))) uint32_t*)(p))
#define AS3(p)  ((__attribute__((address_space(3))) uint32_t*)(p))

struct Params {
  const f16* wt0; const f16* wt1; const f16* wt2;
  const float* bq; const f16* x16;
  f16* hs0; f16* hs1;            // time-indexed inter-layer hin arrays
  f16* ring;                     // [3][RS_][B][H] intra-layer recurrence rings
  const f16* zpad; unsigned* cnt; unsigned* flgW; unsigned* claim; float* out;
};

__device__ __forceinline__ float sigmoid_f(float x) { return 1.f / (1.f + __expf(-x)); }
__device__ __forceinline__ float tanh_f(float x) {
  x = fminf(15.f, fmaxf(-15.f, x));
  float e = __expf(2.f * x);
  return (e - 1.f) / (e + 1.f);
}

// Weights -> fp16, transposed [n'][k], gate-interleaved cols n' = 4*j + g.
__global__ void conv_w(const float* __restrict__ Wi, const float* __restrict__ Wh,
                       int in_dim, int hoff, int Kp, f16* __restrict__ dst) {
  __shared__ f16 tile[64][66];
  const int k0 = blockIdx.x * 64;
  const int by = blockIdx.y;            // 0..47
  const int g = by / 12, j0 = (by % 12) * 64;
  const int tid = threadIdx.x;
  #pragma unroll
  for (int it = 0; it < 16; ++it) {
    int idx = it * 256 + tid;
    int jj = idx & 63;
    int kk = idx >> 6;
    int k = k0 + kk;
    int oc = g * H_ + j0 + jj;
    float v = 0.f;
    if (k < in_dim) v = Wi[(size_t)k * NG_ + oc];
    else if (k >= hoff && k < hoff + H_) v = Wh[(size_t)(k - hoff) * NG_ + oc];
    tile[kk][jj] = (f16)v;
  }
  __syncthreads();
  #pragma unroll
  for (int it = 0; it < 16; ++it) {
    int idx = it * 256 + tid;
    int kk = idx & 63;
    int jj = idx >> 6;
    int np = 4 * (j0 + jj) + g;
    dst[(size_t)np * Kp + k0 + kk] = tile[kk][jj];
  }
}

__global__ void conv_b(const float* __restrict__ b0, const float* __restrict__ b1,
                       const float* __restrict__ b2, float* __restrict__ bq) {
  int id = blockIdx.x * 256 + threadIdx.x;
  if (id < 3 * NG_) {
    int l = id / NG_, np = id % NG_;
    int j = np >> 2, g = np & 3;
    const float* s = (l == 0) ? b0 : (l == 1 ? b1 : b2);
    bq[id] = s[g * H_ + j];
  }
}

// x [B,T,40] fp32 -> x16 [T,B,48] fp16 (cols 40..47 zero)
__global__ void conv_x(const float* __restrict__ x, f16* __restrict__ x16) {
  int id = blockIdx.x * 256 + threadIdx.x;
  if (id >= T_ * B_ * XC_) return;
  int k = id % XC_;
  int b = (id / XC_) % B_;
  int t = id / (XC_ * B_);
  float v = (k < DIN_) ? x[(size_t)b * (T_ * DIN_) + t * DIN_ + k] : 0.f;
  x16[id] = (f16)v;
}

template<int L>
__device__ __forceinline__ void run_layer(
    const f16* __restrict__ WT, const f16* __restrict__ hin, f16* __restrict__ hs_out,
    f16* __restrict__ ring,
    const float* __restrict__ bql, const f16* __restrict__ zpad, float* __restrict__ out,
    unsigned* flg, unsigned* flgW, unsigned& iter, f16* Abuf, float* zred, float* bqs,
    int tid, int lane, int w, int kw, int cw, int btile, int ntile, int n0) {
  constexpr int KP  = (L == 0) ? KP0_ : KP12_;
  constexpr int KQ  = KP / 4;                 // k per wave (4-way k-split)
  constexpr int NKT = KQ / 32;                // 32-k tiles per wave: L0=8, L12=12
  constexpr int CH  = (L == 0) ? 128 : 96;    // 16B chunks per A row in addressed block

  if (tid < 96) bqs[tid] = bql[tid];

  // ---- persistent B fragments (r10-proven mapping): 144 VGPR max
  half8 breg[3 * NKT];
  #pragma unroll
  for (int ct = 0; ct < 3; ++ct) {
    #pragma unroll
    for (int kt = 0; kt < NKT; ++kt) {
      int col = n0 + cw * 48 + ct * 16 + (lane & 15);
      int k = kw * KQ + kt * 32 + (lane >> 4) * 8;
      breg[ct * NKT + kt] = *(const half8*)(WT + (size_t)col * KP + k);
    }
  }

  // hin staging by waves 6,7: previous layer's time-indexed output (stable).
  auto stage_hin = [&](int slot) {
    #pragma unroll
    for (int i = 0; i < 24; ++i) {
      int cb = (w - 6) * 1536 + i * 64;
      int idx = cb + lane;
      int row = idx / 96;
      int c = idx - row * 96;
      int cg = c ^ (row & 7);
      const f16* src = hin + ((size_t)slot * B_ + btile * 32 + row) * H_ + cg * 8;
      __builtin_amdgcn_global_load_lds(AS1C(src), AS3(Abuf + (size_t)cb * 8), 16, 0, 0);
    }
  };
  if (L > 0 && tid >= 384) stage_hin(1);   // prime h_{l-1}(0) for step 0

  // one gate item per thread (tid<384): row*12+jp; 8 gate cols = 2 h cols
  const int grow = tid / 12, gjp = tid - grow * 12;
  const int gb = btile * 32 + grow;
  const int ghc0 = ntile * 24 + 2 * gjp;
  float c0 = 0.f, c1 = 0.f, oa0 = 0.f, oa1 = 0.f;

  for (int t = 0; t < T_; ++t) {
    const int rslot = t & (RS_ - 1);
    // ---- step-start staging (recurrence reads from the L2-hot ring)
    if (L == 0) {
      #pragma unroll
      for (int i = 0; i < 8; ++i) {
        int cb = w * 512 + i * 64;
        int idx = cb + lane;
        int row = idx >> 7;
        int c = idx & 127;
        int cg = c ^ (row & 7);
        int b = btile * 32 + row;
        const f16* src;
        if (cg < 6)        src = hin + ((size_t)t * B_ + b) * XC_ + cg * 8;   // x16
        else if (cg < 102) src = ring + ((size_t)rslot * B_ + b) * H_ + (cg - 6) * 8;
        else               src = zpad;
        __builtin_amdgcn_global_load_lds(AS1C(src), AS3(Abuf + (size_t)cb * 8), 16, 0, 0);
      }
    } else if (w >= 4) {
      #pragma unroll
      for (int i = 0; i < 12; ++i) {
        int cb = (w - 4) * 768 + i * 64;
        int idx = cb + lane;
        int row = idx / 96;
        int c = idx - row * 96;
        int cg = c ^ (row & 7);
        const f16* src = ring + ((size_t)rslot * B_ + btile * 32 + row) * H_ + cg * 8;
        __builtin_amdgcn_global_load_lds(AS1C(src), AS3(Abuf + (size_t)(32 * 768 + cb * 8)), 16, 0, 0);
      }
    }
    asm volatile("s_waitcnt vmcnt(0)" ::: "memory");
    __syncthreads();

    // ---- MFMA: wave tile 32 rows x 48 cols over its k-quarter
    f32x4 acc[2][3] = {};
    const char* Ab = (const char*)(Abuf + (L == 0 ? 0 : (kw >> 1) * 32 * 768));
    const int cbase = (L == 0) ? kw * 32 : (kw & 1) * 48;
    #pragma unroll
    for (int kt = 0; kt < NKT; ++kt) {
      int c = cbase + kt * 4 + (lane >> 4);
      int row0 = (lane & 15);
      half8 a0 = *(const half8*)(Ab + (size_t)row0 * (CH * 16) + (size_t)(c ^ (row0 & 7)) * 16);
      int row1 = 16 + (lane & 15);
      half8 a1 = *(const half8*)(Ab + (size_t)row1 * (CH * 16) + (size_t)(c ^ (row1 & 7)) * 16);
      #pragma unroll
      for (int ct = 0; ct < 3; ++ct) {
        acc[0][ct] = __builtin_amdgcn_mfma_f32_16x16x32_f16(a0, breg[ct * NKT + kt], acc[0][ct], 0, 0, 0);
        acc[1][ct] = __builtin_amdgcn_mfma_f32_16x16x32_f16(a1, breg[ct * NKT + kt], acc[1][ct], 0, 0, 0);
      }
    }

    // ---- partial Z -> LDS, stride-100 rows (100 mod 32 = 25: writes 2-way = free)
    {
      float* zr = zred + (size_t)kw * ZP_;
      #pragma unroll
      for (int rt = 0; rt < 2; ++rt) {
        #pragma unroll
        for (int ct = 0; ct < 3; ++ct) {
          int row = rt * 16 + (lane >> 4) * 4;
          int col = cw * 48 + ct * 16 + (lane & 15);
          #pragma unroll
          for (int r4 = 0; r4 < 4; ++r4)
            zr[(size_t)(row + r4) * 100 + col] = acc[rt][ct][r4];
        }
      }
    }
    __syncthreads();

    // ---- gates (tid<384); waves 6,7 idle here (their prefetch moved post-sync)
    if (tid < 384) {
      const float* z = zred + (size_t)grow * 100 + (size_t)gjp * 8;
      f32x4 za = *(const f32x4*)(z)            + *(const f32x4*)(z + ZP_)
               + *(const f32x4*)(z + 2 * ZP_)  + *(const f32x4*)(z + 3 * ZP_);
      f32x4 zb = *(const f32x4*)(z + 4)           + *(const f32x4*)(z + 4 + ZP_)
               + *(const f32x4*)(z + 4 + 2 * ZP_) + *(const f32x4*)(z + 4 + 3 * ZP_);
      za += *(const f32x4*)(bqs + gjp * 8);
      zb += *(const f32x4*)(bqs + gjp * 8 + 4);
      float i0 = sigmoid_f(za[0]), f0 = sigmoid_f(za[1]), g0 = tanh_f(za[2]), o0 = sigmoid_f(za[3]);
      float i1 = sigmoid_f(zb[0]), f1 = sigmoid_f(zb[1]), g1 = tanh_f(zb[2]), o1 = sigmoid_f(zb[3]);
      float cn0 = f0 * c0 + i0 * g0;
      float cn1 = f1 * c1 + i1 * g1;
      c0 = cn0; c1 = cn1;
      float h0 = o0 * tanh_f(cn0);
      float h1 = o1 * tanh_f(cn1);
      f16 hh0 = (f16)h0, hh1 = (f16)h1;
      unsigned u = ((unsigned)__builtin_bit_cast(uint16_t, hh1) << 16)
                 |  (unsigned)__builtin_bit_cast(uint16_t, hh0);
      unsigned* rp = (unsigned*)(ring + ((size_t)((t + 1) & (RS_ - 1)) * B_ + gb) * H_ + ghc0);
      __hip_atomic_store(rp, u, __ATOMIC_RELAXED, __HIP_MEMORY_SCOPE_WORKGROUP);
      if (L < 2) {
        unsigned* hp = (unsigned*)(hs_out + (size_t)(t + 1) * BH_ + (size_t)gb * H_ + ghc0);
        __hip_atomic_store(hp, u, __ATOMIC_RELAXED, __HIP_MEMORY_SCOPE_WORKGROUP);
      } else {
        oa0 += h0; oa1 += h1;
        if (t == T_ - 1) {
          out[(size_t)gb * H_ + ghc0]     = oa0 * (1.f / T_);
          out[(size_t)gb * H_ + ghc0 + 1] = oa1 * (1.f / T_);
        }
      }
      asm volatile("s_waitcnt vmcnt(0)" ::: "memory");   // h-stores in L2 before flag
    }
    __syncthreads();
    ++iter;
    // ---- two-tier barrier with replica-retry fast path.
    //  Producers: 8 workgroup-scope replica flags (rotating addresses, local L2)
    //  + 1 agent flag (L3 fallback). Poller: retry r reads replica r -- a FRESH
    //  address every retry => never served stale from own L1 (r8 lesson).
    //  Monotone values => stale line can only be a false negative (safe).
    //  Waves 6,7 issue the hin(t+2) prefetch NOW, overlapping the poll; the
    //  final __syncthreads drains it concurrently with the poll wait.
    if (w == 5) {
      unsigned* myrow = flgW + ((size_t)(iter & (FR_ - 1)) * 32 + ntile) * REP_ * 32;
      if (lane < REP_)
        __hip_atomic_store(myrow + (size_t)lane * 32, iter,
                           __ATOMIC_RELAXED, __HIP_MEMORY_SCOPE_WORKGROUP);
      if (lane == 0)
        __hip_atomic_store(flg + (size_t)ntile * 32, iter,
                           __ATOMIC_RELAXED, __HIP_MEMORY_SCOPE_AGENT);
      asm volatile("s_waitcnt vmcnt(0)" ::: "memory");   // replicas visible in L2
      bool done = false;
      #pragma unroll
      for (int r = 0; r < REP_; ++r) {
        volatile const unsigned* fw =
            flgW + (((size_t)(iter & (FR_ - 1)) * 32 + (lane & 31)) * REP_ + r) * 32;
        unsigned v = *fw;
        if (__ballot(v >= iter) == ~0ull) { done = true; break; }
      }
      if (!done) {
        unsigned* fp = flg + (size_t)(lane & 31) * 32;
        for (;;) {
          unsigned v = __hip_atomic_load(fp, __ATOMIC_RELAXED, __HIP_MEMORY_SCOPE_AGENT);
          if (__ballot(v >= iter) == ~0ull) break;
          __builtin_amdgcn_s_sleep(1);
        }
      }
    } else if (L > 0 && w >= 6 && t + 1 < T_) {
      stage_hin(t + 2);   // overlaps the poll; drained by the sync below
    }
    __syncthreads();
  }
}

__global__ __launch_bounds__(512, 2) void lstm_main(Params p) {
  __shared__ __align__(16) f16 Abuf[2 * 32 * 768];        // 96 KB
  __shared__ __align__(16) float zred[4 * ZP_];           // 51.2 KB (stride-100)
  __shared__ __align__(16) float bqs[96];
  __shared__ unsigned claim_s[2];

  const int tid = threadIdx.x;
  const int lane = tid & 63;
  const int w = tid >> 6;
  const int kw = w >> 1, cw = w & 1;

  // dynamic XCD-local grouping (r8-r10 proven)
  if (tid == 0) {
    unsigned xcc;
    asm volatile("s_getreg_b32 %0, hwreg(HW_REG_XCC_ID)" : "=s"(xcc));
    xcc &= 7u;
    unsigned slot = __hip_atomic_fetch_add(p.claim + xcc, 1u,
                                           __ATOMIC_RELAXED, __HIP_MEMORY_SCOPE_AGENT);
    claim_s[0] = xcc;
    claim_s[1] = slot & 31u;
  }
  __syncthreads();
  const int btile = (int)claim_s[0];
  const int ntile = (int)claim_s[1];
  unsigned* flg  = p.cnt  + (size_t)btile * 1024;
  unsigned* flgW = p.flgW + (size_t)btile * ((size_t)FR_ * 32 * REP_ * 32);
  const int n0 = ntile * 96;
  unsigned iter = 0;

  f16* ring0 = p.ring;
  f16* ring1 = p.ring + (size_t)RS_ * BH_;
  f16* ring2 = p.ring + (size_t)2 * RS_ * BH_;

  run_layer<0>(p.wt0, p.x16, p.hs0, ring0, p.bq + 0 * NG_ + n0, p.zpad, p.out, flg, flgW, iter,
               Abuf, zred, bqs, tid, lane, w, kw, cw, btile, ntile, n0);
  run_layer<1>(p.wt1, p.hs0, p.hs1, ring1, p.bq + 1 * NG_ + n0, p.zpad, p.out, flg, flgW, iter,
               Abuf, zred, bqs, tid, lane, w, kw, cw, btile, ntile, n0);
  run_layer<2>(p.wt2, p.hs1, (f16*)nullptr, ring2, p.bq + 2 * NG_ + n0, p.zpad, p.out, flg, flgW, iter,
               Abuf, zred, bqs, tid, lane, w, kw, cw, btile, ntile, n0);
}

extern "C" void kernel_launch(void* const* d_in, const int* in_sizes, int n_in,
                              void* d_out, int out_size, void* d_ws, size_t ws_size,
                              hipStream_t stream) {
  const float* x   = (const float*)d_in[0];
  const float* Wi0 = (const float*)d_in[1];
  const float* Wh0 = (const float*)d_in[2];
  const float* b0  = (const float*)d_in[3];
  const float* Wi1 = (const float*)d_in[4];
  const float* Wh1 = (const float*)d_in[5];
  const float* b1  = (const float*)d_in[6];
  const float* Wi2 = (const float*)d_in[7];
  const float* Wh2 = (const float*)d_in[8];
  const float* b2  = (const float*)d_in[9];

  char* wsb = (char*)d_ws;
  size_t off = 0;
  auto nxt = [&](size_t sz) { char* p = wsb + off; off += (sz + 255) & ~(size_t)255; return p; };
  const size_t flgw_bytes = (size_t)8 * FR_ * 32 * REP_ * 128;   // 16 MB
  f16*      wt0  = (f16*)nxt((size_t)NG_ * KP0_ * 2);
  f16*      wt1  = (f16*)nxt((size_t)NG_ * KP12_ * 2);
  f16*      wt2  = (f16*)nxt((size_t)NG_ * KP12_ * 2);
  float*    bq   = (float*)nxt((size_t)3 * NG_ * 4);
  f16*      x16  = (f16*)nxt((size_t)T_ * B_ * XC_ * 2);
  f16*      hs0  = (f16*)nxt((size_t)(T_ + 1) * BH_ * 2);
  f16*      hs1  = (f16*)nxt((size_t)(T_ + 1) * BH_ * 2);
  f16*      ring = (f16*)nxt((size_t)3 * RS_ * BH_ * 2);
  f16*      zpad = (f16*)nxt(256);
  unsigned* cnt  = (unsigned*)nxt(8 * 1024 * 4);
  unsigned* flgW = (unsigned*)nxt(flgw_bytes);
  unsigned* claim= (unsigned*)nxt(256);
  if (off > ws_size) return;

  hipMemsetAsync(ring, 0, BH_ * 2, stream);                          // h0(0)=0
  hipMemsetAsync(ring + (size_t)RS_ * BH_, 0, BH_ * 2, stream);      // h1(0)=0
  hipMemsetAsync(ring + (size_t)2 * RS_ * BH_, 0, BH_ * 2, stream);  // h2(0)=0
  hipMemsetAsync(hs0, 0, BH_ * 2, stream);
  hipMemsetAsync(hs1, 0, BH_ * 2, stream);
  hipMemsetAsync((void*)zpad, 0, 256, stream);
  hipMemsetAsync(cnt, 0, 8 * 1024 * 4, stream);
  hipMemsetAsync(flgW, 0, flgw_bytes, stream);
  hipMemsetAsync(claim, 0, 256, stream);

  hipLaunchKernelGGL(conv_w, dim3(KP0_ / 64, 48), dim3(256), 0, stream, Wi0, Wh0, DIN_, XC_, KP0_, wt0);
  hipLaunchKernelGGL(conv_w, dim3(KP12_ / 64, 48), dim3(256), 0, stream, Wi1, Wh1, H_, H_, KP12_, wt1);
  hipLaunchKernelGGL(conv_w, dim3(KP12_ / 64, 48), dim3(256), 0, stream, Wi2, Wh2, H_, H_, KP12_, wt2);
  hipLaunchKernelGGL(conv_b, dim3((3 * NG_ + 255) / 256), dim3(256), 0, stream, b0, b1, b2, bq);
  hipLaunchKernelGGL(conv_x, dim3((T_ * B_ * XC_ + 255) / 256), dim3(256), 0, stream, x, x16);

  Params prm{wt0, wt1, wt2, bq, x16, hs0, hs1, ring, zpad, cnt, flgW, claim, (float*)d_out};
  hipLaunchKernelGGL(lstm_main, dim3(256), dim3(512), 0, stream, prm);
}